// Round 6
// baseline (407.504 us; speedup 1.0000x reference)
//
#include <hip/hip_runtime.h>
#include <stdint.h>

#define C 128

typedef __attribute__((ext_vector_type(8))) short bf16x8;
typedef __attribute__((ext_vector_type(4))) float f32x4;
typedef __attribute__((ext_vector_type(2))) float f32x2;

// f32 -> bf16 bits, round-to-nearest-even
__device__ __forceinline__ uint32_t f2bf1(float f) {
    uint32_t u = __float_as_uint(f);
    return (u + 0x7FFFu + ((u >> 16) & 1u)) >> 16;
}

// ---------------- key packing ----------------
// level-1 key: b1(1)<<23 | z1(5)<<18 | y1(9)<<9 | x1(9); numeric order == lexicographic
// level-2 key: z2(4)<<16 | y2(8)<<8 | x2(8)               (b2 == 0 for all real rows)

// ================= GEMM slice (device) =================
// g = bf16( relu(X) @ W0 ), one wave = one 16-row tile, ping-pong 2-deep
// register prefetch, grid-strided over tile range [t0,t1). Wt staged into
// smem fragment-major so every B-fragment is a conflict-free ds_read_b128
// with compile-time immediate offset. Works for 256- or 512-thread blocks.
__device__ __forceinline__ void gemm_loadX(const float* __restrict__ X,
                                           int tile, int lm, int kg, float4* pf) {
    const char* xb = (const char*)X + ((size_t)tile*16 + lm)*512 + kg*32;
    #pragma unroll
    for (int ks = 0; ks < 4; ++ks) {
        pf[2*ks]   = *(const float4*)(xb + ks*128);
        pf[2*ks+1] = *(const float4*)(xb + ks*128 + 16);
    }
}

__device__ __forceinline__ void gemm_compute(const float4* pf, const char* wbase,
                                             ushort* __restrict__ g, int tile,
                                             int lm, int kg) {
    bf16x8 af[4];
    #pragma unroll
    for (int ks = 0; ks < 4; ++ks) {
        float4 a = pf[2*ks], b = pf[2*ks+1];
        union { uint32_t u[4]; bf16x8 v; } cv;
        cv.u[0] = f2bf1(fmaxf(a.x,0.f)) | (f2bf1(fmaxf(a.y,0.f)) << 16);
        cv.u[1] = f2bf1(fmaxf(a.z,0.f)) | (f2bf1(fmaxf(a.w,0.f)) << 16);
        cv.u[2] = f2bf1(fmaxf(b.x,0.f)) | (f2bf1(fmaxf(b.y,0.f)) << 16);
        cv.u[3] = f2bf1(fmaxf(b.z,0.f)) | (f2bf1(fmaxf(b.w,0.f)) << 16);
        af[ks] = cv.v;
    }
    ushort* grow = g + (size_t)((size_t)tile*16 + 4*kg)*128 + lm;
    #pragma unroll
    for (int n = 0; n < 8; ++n) {
        bf16x8 b0 = *(const bf16x8*)(wbase + n*256);
        bf16x8 b1 = *(const bf16x8*)(wbase + n*256 + 8192);
        bf16x8 b2 = *(const bf16x8*)(wbase + n*256 + 16384);
        bf16x8 b3 = *(const bf16x8*)(wbase + n*256 + 24576);
        f32x4 acc = (f32x4){0.f, 0.f, 0.f, 0.f};
        acc = __builtin_amdgcn_mfma_f32_16x16x32_bf16(af[0], b0, acc, 0, 0, 0);
        acc = __builtin_amdgcn_mfma_f32_16x16x32_bf16(af[1], b1, acc, 0, 0, 0);
        acc = __builtin_amdgcn_mfma_f32_16x16x32_bf16(af[2], b2, acc, 0, 0, 0);
        acc = __builtin_amdgcn_mfma_f32_16x16x32_bf16(af[3], b3, acc, 0, 0, 0);
        #pragma unroll
        for (int r = 0; r < 4; ++r)
            grow[(size_t)r*128 + 16*n] = (ushort)f2bf1(acc[r]);
    }
}

__device__ void gemm_slice(const float* __restrict__ X,
                           const ushort* __restrict__ Wt,
                           ushort* __restrict__ g, char* smem,
                           int gb, int ngb, int t0, int t1) {
    const int t = threadIdx.x;
    const int nthreads = blockDim.x;
    // stage Wt (32 KB): dst quad q -> [ks][kg][n][sm]; src quad = n*256+sm*16+kc
    for (int q = t; q < 2048; q += nthreads) {
        int ks = q >> 9, kg = (q >> 7) & 3, n = (q >> 4) & 7, sm = q & 15;
        ((uint4*)smem)[q] = ((const uint4*)Wt)[n*256 + sm*16 + ks*4 + kg];
    }
    __syncthreads();                      // per-block barrier (all threads reach)
    const int l = t & 63, wv = t >> 6, nwv = nthreads >> 6;
    const int lm = l & 15, kg = l >> 4;
    const char* wbase = smem + kg*2048 + lm*16;
    const int stride = ngb * nwv;
    int tile = t0 + gb * nwv + wv;

    float4 pfA[8], pfB[8];
    if (tile < t1)          gemm_loadX(X, tile, lm, kg, pfA);
    if (tile + stride < t1) gemm_loadX(X, tile + stride, lm, kg, pfB);
    while (true) {
        if (tile >= t1) break;
        gemm_compute(pfA, wbase, g, tile, lm, kg);
        if (tile + 2*stride < t1) gemm_loadX(X, tile + 2*stride, lm, kg, pfA);
        tile += stride;
        if (tile >= t1) break;
        gemm_compute(pfB, wbase, g, tile, lm, kg);
        if (tile + 2*stride < t1) gemm_loadX(X, tile + 2*stride, lm, kg, pfB);
        tile += stride;
    }
}

// ---------------- scan primitives ----------------
// 256-thread, 4 words/thread (1024 words per scan block)
__device__ __forceinline__ void bscan1_256(const uint32_t* bm, uint32_t* bs,
                                           int blk, uint32_t* s, int t) {
    int base = blk * 1024 + t * 4;
    uint32_t sum = __popc(bm[base]) + __popc(bm[base+1]) +
                   __popc(bm[base+2]) + __popc(bm[base+3]);
    s[t] = sum;
    __syncthreads();
    for (int off = 128; off > 0; off >>= 1) {
        if (t < off) s[t] += s[t + off];
        __syncthreads();
    }
    if (t == 0) bs[blk] = s[0];
}

__device__ __forceinline__ void bscan3_256(const uint32_t* bm, const uint32_t* bs,
                                           uint32_t* wp, int blk, uint32_t* s, int t) {
    int base = blk * 1024 + t * 4;
    uint32_t p0 = __popc(bm[base]),   p1 = __popc(bm[base+1]);
    uint32_t p2 = __popc(bm[base+2]), p3 = __popc(bm[base+3]);
    uint32_t sum = p0 + p1 + p2 + p3;
    s[t] = sum;
    __syncthreads();
    for (int off = 1; off < 256; off <<= 1) {
        uint32_t add = (t >= off) ? s[t - off] : 0u;
        __syncthreads();
        s[t] += add;
        __syncthreads();
    }
    uint32_t ex = s[t] - sum + bs[blk];
    wp[base]   = ex;
    wp[base+1] = ex + p0;
    wp[base+2] = ex + p0 + p1;
    wp[base+3] = ex + p0 + p1 + p2;
}

__device__ __forceinline__ void vscan1_256(const uint32_t* v, uint32_t* bs,
                                           int blk, int n, uint32_t* s, int t) {
    int base = blk * 1024 + t * 4;
    uint32_t sum = 0;
    #pragma unroll
    for (int j = 0; j < 4; j++) sum += (base + j < n) ? v[base + j] : 0u;
    s[t] = sum;
    __syncthreads();
    for (int off = 128; off > 0; off >>= 1) {
        if (t < off) s[t] += s[t + off];
        __syncthreads();
    }
    if (t == 0) bs[blk] = s[0];
}

// 512-thread variants (2 words/thread; same 1024-word block geometry)
__device__ __forceinline__ void blksum_scan_512(uint32_t* bs, uint32_t* total,
                                                int nb, uint32_t* s, int t) {
    uint32_t v = (t < nb) ? bs[t] : 0u;
    s[t] = v;
    __syncthreads();
    for (int off = 1; off < 512; off <<= 1) {
        uint32_t add = (t >= off) ? s[t - off] : 0u;
        __syncthreads();
        s[t] += add;
        __syncthreads();
    }
    if (t < nb) bs[t] = s[t] - v;
    if (t == nb - 1) *total = s[t];
}

__device__ __forceinline__ void vscan1_512(const uint32_t* v, uint32_t* bs,
                                           int blk, int n, uint32_t* s, int t) {
    int base = blk * 1024 + t * 2;
    uint32_t sum = 0;
    if (base     < n) sum += v[base];
    if (base + 1 < n) sum += v[base+1];
    s[t] = sum;
    __syncthreads();
    for (int off = 256; off > 0; off >>= 1) {
        if (t < off) s[t] += s[t + off];
        __syncthreads();
    }
    if (t == 0) bs[blk] = s[0];
}

__device__ __forceinline__ void vscan3_512(const uint32_t* v, const uint32_t* bs,
                                           uint32_t* ex_out, int blk, int n,
                                           uint32_t* s, int t) {
    int base = blk * 1024 + t * 2;
    uint32_t p0 = (base     < n) ? v[base]   : 0u;
    uint32_t p1 = (base + 1 < n) ? v[base+1] : 0u;
    uint32_t sum = p0 + p1;
    s[t] = sum;
    __syncthreads();
    for (int off = 1; off < 512; off <<= 1) {
        uint32_t add = (t >= off) ? s[t - off] : 0u;
        __syncthreads();
        s[t] += add;
        __syncthreads();
    }
    uint32_t e = s[t] - sum + bs[blk];
    if (base     < n) ex_out[base]   = e;
    if (base + 1 < n) ex_out[base+1] = e + p0;
}

// ================= launches =================
// L1: zero the atomic buffers + convert W -> Wt (no gemm; Wt made here)
__global__ __launch_bounds__(256) void zeroconv_kernel(
    uint4* __restrict__ zbase, int nquads,
    const float* __restrict__ W, ushort* __restrict__ Wt, int nzb) {
    int b = blockIdx.x, t = threadIdx.x;
    if (b < nzb) {
        int i = b * 256 + t;
        if (i < nquads) zbase[i] = (uint4){0u, 0u, 0u, 0u};
    } else {
        int id = (b - nzb) * 256 + t;                  // 0..16383
        int n = id >> 7, k = id & 127;
        Wt[id] = (ushort)f2bf1(W[k * C + n]);
    }
}

// L2: mark bitmap bits || gemm slice
__global__ __launch_bounds__(256) void markg_kernel(
    const int* __restrict__ coords, uint32_t* __restrict__ bm1,
    uint32_t* __restrict__ bm2, int M, int nprep,
    const float* __restrict__ X, const ushort* __restrict__ Wt,
    ushort* __restrict__ g, int ngb, int t0, int t1) {
    __shared__ __align__(16) char smem[32768];
    int b = blockIdx.x;
    if (b >= nprep) { gemm_slice(X, Wt, g, smem, b - nprep, ngb, t0, t1); return; }
    int i = b * 256 + threadIdx.x;
    if (i >= M) return;
    int bb = coords[4*i+0], z = coords[4*i+1], y = coords[4*i+2], x = coords[4*i+3];
    uint32_t k1 = ((uint32_t)(bb>>1)<<23) | ((uint32_t)(z>>1)<<18) |
                  ((uint32_t)(y>>1)<<9)  | (uint32_t)(x>>1);
    uint32_t k2 = ((uint32_t)(z>>2)<<16) | ((uint32_t)(y>>2)<<8) | (uint32_t)(x>>2);
    atomicOr(&bm1[k1>>5], 1u << (k1 & 31));
    atomicOr(&bm2[k2>>5], 1u << (k2 & 31));
}

// L3: bitmap scan phase1 (bm1 blocks [0,512), bm2 [512,544)) || gemm slice
__global__ __launch_bounds__(256) void mscan1g_kernel(
    const uint32_t* __restrict__ bm1, uint32_t* __restrict__ bs1,
    const uint32_t* __restrict__ bm2, uint32_t* __restrict__ bs2, int nprep,
    const float* __restrict__ X, const ushort* __restrict__ Wt,
    ushort* __restrict__ g, int ngb, int t0, int t1) {
    __shared__ __align__(16) char smem[32768];
    int b = blockIdx.x, t = threadIdx.x;
    if (b >= nprep) { gemm_slice(X, Wt, g, smem, b - nprep, ngb, t0, t1); return; }
    uint32_t* s = (uint32_t*)smem;
    if (b < 512) bscan1_256(bm1, bs1, b, s, t);
    else         bscan1_256(bm2, bs2, b - 512, s, t);
}

// L4: block-sum scans (bs1 nb=512, bs2 nb=32) || gemm slice  [512 threads]
__global__ __launch_bounds__(512) void mscan2g_kernel(
    uint32_t* __restrict__ bs1, uint32_t* __restrict__ bs2,
    uint32_t* __restrict__ totals, int nprep,
    const float* __restrict__ X, const ushort* __restrict__ Wt,
    ushort* __restrict__ g, int ngb, int t0, int t1) {
    __shared__ __align__(16) char smem[32768];
    int b = blockIdx.x, t = threadIdx.x;
    if (b >= nprep) { gemm_slice(X, Wt, g, smem, b - nprep, ngb, t0, t1); return; }
    uint32_t* s = (uint32_t*)smem;
    if (b == 0) blksum_scan_512(bs1, &totals[0], 512, s, t);
    else        blksum_scan_512(bs2, &totals[1], 32,  s, t);
}

// L5: bitmap scan phase3 -> wp1/wp2 || gemm slice
__global__ __launch_bounds__(256) void mscan3g_kernel(
    const uint32_t* __restrict__ bm1, const uint32_t* __restrict__ bs1,
    uint32_t* __restrict__ wp1,
    const uint32_t* __restrict__ bm2, const uint32_t* __restrict__ bs2,
    uint32_t* __restrict__ wp2, int nprep,
    const float* __restrict__ X, const ushort* __restrict__ Wt,
    ushort* __restrict__ g, int ngb, int t0, int t1) {
    __shared__ __align__(16) char smem[32768];
    int b = blockIdx.x, t = threadIdx.x;
    if (b >= nprep) { gemm_slice(X, Wt, g, smem, b - nprep, ngb, t0, t1); return; }
    uint32_t* s = (uint32_t*)smem;
    if (b < 512) bscan3_256(bm1, bs1, wp1, b, s, t);
    else         bscan3_256(bm2, bs2, wp2, b - 512, s, t);
}

// L6: per-row rank1 -> counts + slot (atomic return) || gemm slice
__global__ __launch_bounds__(256) void countg_kernel(
    const int* __restrict__ coords, const uint32_t* __restrict__ bm1,
    const uint32_t* __restrict__ wp1, uint32_t* __restrict__ counts,
    uint32_t* __restrict__ rank1_arr, uint32_t* __restrict__ slot1, int M, int nprep,
    const float* __restrict__ X, const ushort* __restrict__ Wt,
    ushort* __restrict__ g, int ngb, int t0, int t1) {
    __shared__ __align__(16) char smem[32768];
    int b = blockIdx.x;
    if (b >= nprep) { gemm_slice(X, Wt, g, smem, b - nprep, ngb, t0, t1); return; }
    int i = b * 256 + threadIdx.x;
    if (i >= M) return;
    int bb = coords[4*i+0], z = coords[4*i+1], y = coords[4*i+2], x = coords[4*i+3];
    uint32_t k1 = ((uint32_t)(bb>>1)<<23) | ((uint32_t)(z>>1)<<18) |
                  ((uint32_t)(y>>1)<<9)  | (uint32_t)(x>>1);
    uint32_t r1 = wp1[k1>>5] + __popc(bm1[k1>>5] & ((1u << (k1 & 31)) - 1u));
    rank1_arr[i] = r1;
    slot1[i] = atomicAdd(&counts[r1], 1u);
}

// L7: vscan1(counts->bsc) [0,nbc) || childsum [nbc,nbc+2048) || gemm slice
__global__ __launch_bounds__(256) void mk1g_kernel(
    const uint32_t* __restrict__ counts, uint32_t* __restrict__ bsc,
    const uint32_t* __restrict__ bm1, const uint32_t* __restrict__ wp1,
    const uint32_t* __restrict__ bm2, const uint32_t* __restrict__ wp2,
    uint32_t* __restrict__ parent_r2, uint32_t* __restrict__ rowcounts2,
    uint32_t* __restrict__ childbase, int M, int nbc, int nwords, int nprep,
    const float* __restrict__ X, const ushort* __restrict__ Wt,
    ushort* __restrict__ g, int ngb, int t0, int t1) {
    __shared__ __align__(16) char smem[32768];
    int b = blockIdx.x, t = threadIdx.x;
    if (b >= nprep) { gemm_slice(X, Wt, g, smem, b - nprep, ngb, t0, t1); return; }
    if (b < nbc) {
        vscan1_256(counts, bsc, b, M, (uint32_t*)smem, t);
        return;
    }
    int w = (b - nbc) * 256 + t;
    if (w >= nwords) return;
    uint32_t bits = bm1[w];
    if (!bits) return;
    uint32_t r1 = wp1[w];
    while (bits) {
        int bit = __ffs(bits) - 1;
        uint32_t k1 = ((uint32_t)w << 5) | (uint32_t)bit;
        uint32_t z1 = (k1 >> 18) & 31u, y1 = (k1 >> 9) & 511u, x1 = k1 & 511u;
        uint32_t k2 = ((z1 >> 1) << 16) | ((y1 >> 1) << 8) | (x1 >> 1);
        uint32_t word2 = bm2[k2 >> 5];
        uint32_t r2 = wp2[k2 >> 5] + __popc(word2 & ((1u << (k2 & 31)) - 1u));
        parent_r2[r1] = r2;
        childbase[r1] = atomicAdd(&rowcounts2[r2], counts[r1]);
        r1++;
        bits &= bits - 1;
    }
}

// L8: blksum(bsc->totals2) || vscan1(rowcounts2->bsc2) || gemm slice [512 thr]
__global__ __launch_bounds__(512) void mk2g_kernel(
    uint32_t* __restrict__ bsc, uint32_t* __restrict__ totals,
    const uint32_t* __restrict__ rowcounts2, uint32_t* __restrict__ bsc2,
    int M, int nbc, int nprep,
    const float* __restrict__ X, const ushort* __restrict__ Wt,
    ushort* __restrict__ g, int ngb, int t0, int t1) {
    __shared__ __align__(16) char smem[32768];
    int b = blockIdx.x, t = threadIdx.x;
    if (b >= nprep) { gemm_slice(X, Wt, g, smem, b - nprep, ngb, t0, t1); return; }
    uint32_t* s = (uint32_t*)smem;
    if (b == 0) blksum_scan_512(bsc, &totals[2], nbc, s, t);
    else        vscan1_512(rowcounts2, bsc2, b - 1, M, s, t);
}

// L9: vscan3(counts->start1) [0,nbc) || blksum(bsc2->totals3) || gemm slice [512]
__global__ __launch_bounds__(512) void mk3g_kernel(
    const uint32_t* __restrict__ counts, const uint32_t* __restrict__ bsc,
    uint32_t* __restrict__ start1,
    uint32_t* __restrict__ bsc2, uint32_t* __restrict__ totals,
    int M, int nbc, int nprep,
    const float* __restrict__ X, const ushort* __restrict__ Wt,
    ushort* __restrict__ g, int ngb, int t0, int t1) {
    __shared__ __align__(16) char smem[32768];
    int b = blockIdx.x, t = threadIdx.x;
    if (b >= nprep) { gemm_slice(X, Wt, g, smem, b - nprep, ngb, t0, t1); return; }
    uint32_t* s = (uint32_t*)smem;
    if (b < nbc) vscan3_512(counts, bsc, start1, b, M, s, t);
    else         blksum_scan_512(bsc2, &totals[3], nbc, s, t);
}

// L10: perm scatter [0,npb) || vscan3(rowcounts2->rowstart2) || gemm slice [512]
__global__ __launch_bounds__(512) void mk4g_kernel(
    const uint32_t* __restrict__ rank1_arr, const uint32_t* __restrict__ start1,
    const uint32_t* __restrict__ slot1, uint32_t* __restrict__ perm,
    const uint32_t* __restrict__ rowcounts2, const uint32_t* __restrict__ bsc2,
    uint32_t* __restrict__ rowstart2, int M, int npb, int nbc, int nprep,
    const float* __restrict__ X, const ushort* __restrict__ Wt,
    ushort* __restrict__ g, int ngb, int t0, int t1) {
    __shared__ __align__(16) char smem[32768];
    int b = blockIdx.x, t = threadIdx.x;
    if (b >= nprep) { gemm_slice(X, Wt, g, smem, b - nprep, ngb, t0, t1); return; }
    if (b < npb) {
        int i = b * 512 + t;
        if (i >= M) return;
        uint32_t r1 = rank1_arr[i];
        perm[start1[r1] + slot1[i]] = i;
        return;
    }
    vscan3_512(rowcounts2, bsc2, rowstart2, b - npb, M, (uint32_t*)smem, t);
}

// L11: flatten rows grouped by r2 (atomic-free) || gemm slice [512]
__global__ __launch_bounds__(512) void flatteng_kernel(
    const uint32_t* __restrict__ parent_r2, const uint32_t* __restrict__ counts,
    const uint32_t* __restrict__ start1, const uint32_t* __restrict__ rowstart2,
    const uint32_t* __restrict__ childbase, const uint32_t* __restrict__ perm,
    uint32_t* __restrict__ perm_f, const uint32_t* __restrict__ totals, int M,
    int nprep,
    const float* __restrict__ X, const ushort* __restrict__ Wt,
    ushort* __restrict__ g, int ngb, int t0, int t1) {
    __shared__ __align__(16) char smem[32768];
    int b = blockIdx.x;
    if (b >= nprep) { gemm_slice(X, Wt, g, smem, b - nprep, ngb, t0, t1); return; }
    int i = b * 512 + threadIdx.x;
    if (i >= M) return;
    uint32_t U1 = totals[0];
    if ((uint32_t)i >= U1) return;
    uint32_t r2 = parent_r2[i];
    uint32_t cnt = counts[i];
    uint32_t dst = rowstart2[r2] + childbase[i];
    uint32_t s = start1[i];
    perm_f[dst] = perm[s] | 0x80000000u;               // flag = start of relu group
    for (uint32_t q = 1; q < cnt; ++q) perm_f[dst + q] = perm[s + q];
}

// L12: flattened gather: out[j] = sum_groups relu(sum_rows g)
__global__ __launch_bounds__(256) void gather2_kernel(
    const uint32_t* __restrict__ rowstart2, const uint32_t* __restrict__ rowcounts2,
    const uint32_t* __restrict__ perm_f, const ushort* __restrict__ g,
    float* __restrict__ out, int M) {
    int wid = (blockIdx.x * 256 + threadIdx.x) >> 6;
    wid = __builtin_amdgcn_readfirstlane(wid);         // force wave-uniform SGPR
    int lane = threadIdx.x & 63;
    if (wid >= M) return;
    const uint32_t* G = (const uint32_t*)g;
    float accx = 0.f, accy = 0.f;
    uint32_t n = rowcounts2[wid];
    if (n) {
        uint32_t s = rowstart2[wid];
        uint32_t ev = (lane < (int)n) ? perm_f[s + lane] : 0u;
        float sx = 0.f, sy = 0.f;
        uint32_t ecur = (uint32_t)__shfl((int)ev, 0);
        uint32_t pk = G[(size_t)(ecur & 0x7FFFFFFFu) * 64 + lane];
        for (uint32_t q = 1; q < n; ++q) {
            uint32_t en = (q < 64u) ? (uint32_t)__shfl((int)ev, (int)q)
                                    : perm_f[s + q];
            uint32_t pkn = G[(size_t)(en & 0x7FFFFFFFu) * 64 + lane];
            sx += __uint_as_float(pk << 16);
            sy += __uint_as_float(pk & 0xFFFF0000u);
            if (en >> 31) {
                accx += fmaxf(sx, 0.f); accy += fmaxf(sy, 0.f);
                sx = 0.f; sy = 0.f;
            }
            pk = pkn;
        }
        sx += __uint_as_float(pk << 16);
        sy += __uint_as_float(pk & 0xFFFF0000u);
        accx += fmaxf(sx, 0.f);
        accy += fmaxf(sy, 0.f);
    }
    f32x2 o; o[0] = accx; o[1] = accy;
    __builtin_nontemporal_store(o, (f32x2*)out + (size_t)wid * 64 + lane);
}

extern "C" void kernel_launch(void* const* d_in, const int* in_sizes, int n_in,
                              void* d_out, int out_size, void* d_ws, size_t ws_size,
                              hipStream_t stream) {
    const float* X      = (const float*)d_in[0];
    const int*   coords = (const int*)d_in[1];
    const float* W      = (const float*)d_in[2];
    const int M = in_sizes[0] / C;               // 400000

    const int NW1 = 1 << 19;                     // 2^24-bit bitmap -> 524288 words
    const int NW2 = 1 << 15;                     // 2^20-bit bitmap -> 32768 words
    const int NBC = (M + 1023) / 1024;           // 391 scan blocks over M values
    const int NPB256 = (M + 255) / 256;          // 1563
    const int NPB512 = (M + 511) / 512;          // 782

    char* ws = (char*)d_ws;
    size_t off = 0;
    ushort*   g         = (ushort*)(ws + off);   off += (size_t)M * C * 2;   // 102.4 MB
    // ---- contiguous zeroed region: bm1 | bm2 | counts | rowcounts2 ----
    uint32_t* bm1       = (uint32_t*)(ws + off); off += (size_t)NW1 * 4;
    uint32_t* bm2       = (uint32_t*)(ws + off); off += (size_t)NW2 * 4;
    uint32_t* counts    = (uint32_t*)(ws + off); off += (size_t)M * 4;
    uint32_t* rowcounts2= (uint32_t*)(ws + off); off += (size_t)M * 4;
    const size_t zero_off   = (size_t)M * C * 2;
    const size_t zero_bytes = off - zero_off;    // 16B multiple
    // ---- never-zeroed scratch ----
    uint32_t* wp1       = (uint32_t*)(ws + off); off += (size_t)NW1 * 4;
    uint32_t* wp2       = (uint32_t*)(ws + off); off += (size_t)NW2 * 4;
    uint32_t* bs1       = (uint32_t*)(ws + off); off += 512 * 4;
    uint32_t* bs2       = (uint32_t*)(ws + off); off += 512 * 4;
    uint32_t* bsc       = (uint32_t*)(ws + off); off += 512 * 4;
    uint32_t* bsc2      = (uint32_t*)(ws + off); off += 512 * 4;
    uint32_t* totals    = (uint32_t*)(ws + off); off += 4 * 4;
    uint32_t* start1    = (uint32_t*)(ws + off); off += (size_t)M * 4;
    uint32_t* rank1_arr = (uint32_t*)(ws + off); off += (size_t)M * 4;
    uint32_t* slot1     = (uint32_t*)(ws + off); off += (size_t)M * 4;
    uint32_t* perm      = (uint32_t*)(ws + off); off += (size_t)M * 4;
    uint32_t* parent_r2 = (uint32_t*)(ws + off); off += (size_t)M * 4;
    uint32_t* childbase = (uint32_t*)(ws + off); off += (size_t)M * 4;
    uint32_t* rowstart2 = (uint32_t*)(ws + off); off += (size_t)M * 4;
    ushort*   Wt        = (ushort*)(ws + off);   off += (size_t)C * C * 2;
    uint32_t* perm_f    = rank1_arr;             // rank1_arr dead after mk4 (perm)

    const int NQ  = (int)(zero_bytes / 16);
    const int NZB = (NQ + 255) / 256;

    // GEMM tile ranges: cumulative % of NT per sliced launch (sums to 100)
    const int NT = M >> 4;                       // 25000 row-tiles
    auto cut = [&](int pct) { return (int)((long long)NT * pct / 100); };
    const int c1 = cut(12), c2 = cut(21), c3 = cut(25), c4 = cut(34),
              c5 = cut(46), c6 = cut(59), c7 = cut(63), c8 = cut(67),
              c9 = cut(80);
    const int NG256 = 500, NG512 = 250;          // gemm blocks per launch

    // L1: zero atomic buffers + convert W (Wt ready for all later slices)
    zeroconv_kernel<<<NZB + 64, 256, 0, stream>>>((uint4*)(ws + zero_off), NQ, W, Wt, NZB);
    // L2..L11: prep roles with GEMM slices riding along
    markg_kernel<<<NPB256 + NG256, 256, 0, stream>>>(coords, bm1, bm2, M, NPB256,
                                                     X, Wt, g, NG256, 0, c1);
    mscan1g_kernel<<<544 + NG256, 256, 0, stream>>>(bm1, bs1, bm2, bs2, 544,
                                                    X, Wt, g, NG256, c1, c2);
    mscan2g_kernel<<<2 + NG512, 512, 0, stream>>>(bs1, bs2, totals, 2,
                                                  X, Wt, g, NG512, c2, c3);
    mscan3g_kernel<<<544 + NG256, 256, 0, stream>>>(bm1, bs1, wp1, bm2, bs2, wp2, 544,
                                                    X, Wt, g, NG256, c3, c4);
    countg_kernel<<<NPB256 + NG256, 256, 0, stream>>>(coords, bm1, wp1, counts,
                                                      rank1_arr, slot1, M, NPB256,
                                                      X, Wt, g, NG256, c4, c5);
    mk1g_kernel<<<NBC + NW1/256 + NG256, 256, 0, stream>>>(
        counts, bsc, bm1, wp1, bm2, wp2, parent_r2, rowcounts2, childbase,
        M, NBC, NW1, NBC + NW1/256, X, Wt, g, NG256, c5, c6);
    mk2g_kernel<<<1 + NBC + NG512, 512, 0, stream>>>(bsc, totals, rowcounts2, bsc2,
                                                     M, NBC, 1 + NBC,
                                                     X, Wt, g, NG512, c6, c7);
    mk3g_kernel<<<NBC + 1 + NG512, 512, 0, stream>>>(counts, bsc, start1, bsc2, totals,
                                                     M, NBC, NBC + 1,
                                                     X, Wt, g, NG512, c7, c8);
    mk4g_kernel<<<NPB512 + NBC + NG512, 512, 0, stream>>>(
        rank1_arr, start1, slot1, perm, rowcounts2, bsc2, rowstart2,
        M, NPB512, NBC, NPB512 + NBC, X, Wt, g, NG512, c8, c9);
    flatteng_kernel<<<NPB512 + NG512, 512, 0, stream>>>(
        parent_r2, counts, start1, rowstart2, childbase, perm, perm_f, totals, M,
        NPB512, X, Wt, g, NG512, c9, NT);
    // L12: gather
    gather2_kernel<<<(M + 3) / 4, 256, 0, stream>>>(
        rowstart2, rowcounts2, perm_f, g, (float*)d_out, M);
}

// Round 7
// 245.641 us; speedup vs baseline: 1.6589x; 1.6589x over previous
//
#include <hip/hip_runtime.h>
#include <stdint.h>

#define C 128

typedef __attribute__((ext_vector_type(8))) short bf16x8;
typedef __attribute__((ext_vector_type(4))) float f32x4;
typedef __attribute__((ext_vector_type(2))) float f32x2;

// f32 -> bf16 bits, round-to-nearest-even
__device__ __forceinline__ uint32_t f2bf1(float f) {
    uint32_t u = __float_as_uint(f);
    return (u + 0x7FFFu + ((u >> 16) & 1u)) >> 16;
}

// ---------------- key packing ----------------
// level-1 key: b1(1)<<23 | z1(5)<<18 | y1(9)<<9 | x1(9); numeric order == lexicographic
// level-2 key: z2(4)<<16 | y2(8)<<8 | x2(8)               (b2 == 0 for all real rows)

// ---- merged: zero the atomic buffers (blocks 0..nzb-1) + convert W -> Wt bf16 ----
__global__ __launch_bounds__(512) void zeroconv_kernel(
    uint4* __restrict__ zbase, int nquads,
    const float* __restrict__ W, ushort* __restrict__ Wt, int nzb) {
    int b = blockIdx.x, t = threadIdx.x;
    if (b < nzb) {
        int i = b * 512 + t;
        if (i < nquads) zbase[i] = (uint4){0u, 0u, 0u, 0u};
    } else {
        int id = (b - nzb) * 512 + t;                  // 0..16383
        int n = id >> 7, k = id & 127;
        Wt[id] = (ushort)f2bf1(W[k * C + n]);
    }
}

// ---- mark bitmap bits ----
__global__ __launch_bounds__(512) void mark_kernel(
    const int* __restrict__ coords, uint32_t* __restrict__ bm1,
    uint32_t* __restrict__ bm2, int M) {
    int i = blockIdx.x * 512 + threadIdx.x;
    if (i >= M) return;
    int bb = coords[4*i+0], z = coords[4*i+1], y = coords[4*i+2], x = coords[4*i+3];
    uint32_t k1 = ((uint32_t)(bb>>1)<<23) | ((uint32_t)(z>>1)<<18) |
                  ((uint32_t)(y>>1)<<9)  | (uint32_t)(x>>1);
    uint32_t k2 = ((uint32_t)(z>>2)<<16) | ((uint32_t)(y>>2)<<8) | (uint32_t)(x>>2);
    atomicOr(&bm1[k1>>5], 1u << (k1 & 31));
    atomicOr(&bm2[k2>>5], 1u << (k2 & 31));
}

// ---------------- shared device helpers (512-thread scan primitives) ----------------
__device__ __forceinline__ void bscan1_512(const uint32_t* bm, uint32_t* bs,
                                           int blk, uint32_t* s, int t) {
    int base = blk * 1024 + t * 2;
    uint32_t sum = __popc(bm[base]) + __popc(bm[base+1]);
    s[t] = sum;
    __syncthreads();
    for (int off = 256; off > 0; off >>= 1) {
        if (t < off) s[t] += s[t + off];
        __syncthreads();
    }
    if (t == 0) bs[blk] = s[0];
}

__device__ __forceinline__ void bscan3_512(const uint32_t* bm, const uint32_t* bs,
                                           uint32_t* wp, int blk, uint32_t* s, int t) {
    int base = blk * 1024 + t * 2;
    uint32_t p0 = __popc(bm[base]), p1 = __popc(bm[base+1]);
    uint32_t sum = p0 + p1;
    s[t] = sum;
    __syncthreads();
    for (int off = 1; off < 512; off <<= 1) {
        uint32_t add = (t >= off) ? s[t - off] : 0u;
        __syncthreads();
        s[t] += add;
        __syncthreads();
    }
    uint32_t ex = s[t] - sum + bs[blk];
    wp[base]   = ex;
    wp[base+1] = ex + p0;
}

// single-block exclusive scan of nb<=512 block sums, in place, writes total
__device__ __forceinline__ void blksum_scan_512(uint32_t* bs, uint32_t* total,
                                                int nb, uint32_t* s, int t) {
    uint32_t v = (t < nb) ? bs[t] : 0u;
    s[t] = v;
    __syncthreads();
    for (int off = 1; off < 512; off <<= 1) {
        uint32_t add = (t >= off) ? s[t - off] : 0u;
        __syncthreads();
        s[t] += add;
        __syncthreads();
    }
    if (t < nb) bs[t] = s[t] - v;
    if (t == nb - 1) *total = s[t];
}

__device__ __forceinline__ void vscan1_512(const uint32_t* v, uint32_t* bs,
                                           int blk, int n, uint32_t* s, int t) {
    int base = blk * 1024 + t * 2;
    uint32_t sum = 0;
    if (base     < n) sum += v[base];
    if (base + 1 < n) sum += v[base+1];
    s[t] = sum;
    __syncthreads();
    for (int off = 256; off > 0; off >>= 1) {
        if (t < off) s[t] += s[t + off];
        __syncthreads();
    }
    if (t == 0) bs[blk] = s[0];
}

__device__ __forceinline__ void vscan3_512(const uint32_t* v, const uint32_t* bs,
                                           uint32_t* ex_out, int blk, int n,
                                           uint32_t* s, int t) {
    int base = blk * 1024 + t * 2;
    uint32_t p0 = (base     < n) ? v[base]   : 0u;
    uint32_t p1 = (base + 1 < n) ? v[base+1] : 0u;
    uint32_t sum = p0 + p1;
    s[t] = sum;
    __syncthreads();
    for (int off = 1; off < 512; off <<= 1) {
        uint32_t add = (t >= off) ? s[t - off] : 0u;
        __syncthreads();
        s[t] += add;
        __syncthreads();
    }
    uint32_t e = s[t] - sum + bs[blk];
    if (base     < n) ex_out[base]   = e;
    if (base + 1 < n) ex_out[base+1] = e + p0;
}

// ---- merged bitmap scan phases: blocks [0,512) -> bm1, [512,544) -> bm2 ----
__global__ __launch_bounds__(512) void mscan1_kernel(
    const uint32_t* __restrict__ bm1, uint32_t* __restrict__ bs1,
    const uint32_t* __restrict__ bm2, uint32_t* __restrict__ bs2) {
    __shared__ uint32_t s[512];
    int b = blockIdx.x, t = threadIdx.x;
    if (b < 512) bscan1_512(bm1, bs1, b, s, t);
    else         bscan1_512(bm2, bs2, b - 512, s, t);
}

__global__ __launch_bounds__(512) void mscan2_kernel(
    uint32_t* __restrict__ bs1, uint32_t* __restrict__ bs2,
    uint32_t* __restrict__ totals) {
    __shared__ uint32_t s[512];
    int t = threadIdx.x;
    if (blockIdx.x == 0) blksum_scan_512(bs1, &totals[0], 512, s, t);
    else                 blksum_scan_512(bs2, &totals[1], 32,  s, t);
}

__global__ __launch_bounds__(512) void mscan3_kernel(
    const uint32_t* __restrict__ bm1, const uint32_t* __restrict__ bs1,
    uint32_t* __restrict__ wp1,
    const uint32_t* __restrict__ bm2, const uint32_t* __restrict__ bs2,
    uint32_t* __restrict__ wp2) {
    __shared__ uint32_t s[512];
    int b = blockIdx.x, t = threadIdx.x;
    if (b < 512) bscan3_512(bm1, bs1, wp1, b, s, t);
    else         bscan3_512(bm2, bs2, wp2, b - 512, s, t);
}

// per input row: rank1 -> counts + rank cache; atomic return value IS the slot
__global__ __launch_bounds__(512) void count_kernel(
    const int* __restrict__ coords, const uint32_t* __restrict__ bm1,
    const uint32_t* __restrict__ wp1, uint32_t* __restrict__ counts,
    uint32_t* __restrict__ rank1_arr, uint32_t* __restrict__ slot1, int M) {
    int i = blockIdx.x * 512 + threadIdx.x;
    if (i >= M) return;
    int b = coords[4*i+0], z = coords[4*i+1], y = coords[4*i+2], x = coords[4*i+3];
    uint32_t k1 = ((uint32_t)(b>>1)<<23) | ((uint32_t)(z>>1)<<18) |
                  ((uint32_t)(y>>1)<<9)  | (uint32_t)(x>>1);
    uint32_t r1 = wp1[k1>>5] + __popc(bm1[k1>>5] & ((1u << (k1 & 31)) - 1u));
    rank1_arr[i] = r1;
    slot1[i] = atomicAdd(&counts[r1], 1u);
}

// ---- MK1: blocks [0,nbc) vscan1(counts) ; [nbc, nbc+1024) childsum over bm1 words ----
// childsum atomic return value IS the child's base offset inside the parent segment
__global__ __launch_bounds__(512) void mk1_kernel(
    const uint32_t* __restrict__ counts, uint32_t* __restrict__ bsc,
    const uint32_t* __restrict__ bm1, const uint32_t* __restrict__ wp1,
    const uint32_t* __restrict__ bm2, const uint32_t* __restrict__ wp2,
    uint32_t* __restrict__ parent_r2, uint32_t* __restrict__ rowcounts2,
    uint32_t* __restrict__ childbase, int M, int nbc, int nwords) {
    int b = blockIdx.x, t = threadIdx.x;
    if (b < nbc) {
        __shared__ uint32_t s[512];
        vscan1_512(counts, bsc, b, M, s, t);
        return;
    }
    int w = (b - nbc) * 512 + t;
    if (w >= nwords) return;
    uint32_t bits = bm1[w];
    if (!bits) return;
    uint32_t r1 = wp1[w];
    while (bits) {
        int bit = __ffs(bits) - 1;
        uint32_t k1 = ((uint32_t)w << 5) | (uint32_t)bit;
        uint32_t z1 = (k1 >> 18) & 31u, y1 = (k1 >> 9) & 511u, x1 = k1 & 511u;
        uint32_t k2 = ((z1 >> 1) << 16) | ((y1 >> 1) << 8) | (x1 >> 1);
        uint32_t word2 = bm2[k2 >> 5];
        uint32_t r2 = wp2[k2 >> 5] + __popc(word2 & ((1u << (k2 & 31)) - 1u));
        parent_r2[r1] = r2;
        childbase[r1] = atomicAdd(&rowcounts2[r2], counts[r1]);
        r1++;
        bits &= bits - 1;
    }
}

// ---- MK2: block 0 scan2(bsc->totals[2]) ; blocks [1,1+nbc) vscan1(rowcounts2) ----
__global__ __launch_bounds__(512) void mk2_kernel(
    uint32_t* __restrict__ bsc, uint32_t* __restrict__ totals,
    const uint32_t* __restrict__ rowcounts2, uint32_t* __restrict__ bsc2,
    int M, int nbc) {
    __shared__ uint32_t s[512];
    int b = blockIdx.x, t = threadIdx.x;
    if (b == 0) blksum_scan_512(bsc, &totals[2], nbc, s, t);
    else        vscan1_512(rowcounts2, bsc2, b - 1, M, s, t);
}

// ---- MK3: blocks [0,nbc) vscan3(counts->start1) ; block nbc scan2(bsc2->totals[3]) ----
__global__ __launch_bounds__(512) void mk3_kernel(
    const uint32_t* __restrict__ counts, const uint32_t* __restrict__ bsc,
    uint32_t* __restrict__ start1,
    uint32_t* __restrict__ bsc2, uint32_t* __restrict__ totals,
    int M, int nbc) {
    __shared__ uint32_t s[512];
    int b = blockIdx.x, t = threadIdx.x;
    if (b < nbc) vscan3_512(counts, bsc, start1, b, M, s, t);
    else         blksum_scan_512(bsc2, &totals[3], nbc, s, t);
}

// ---- MK4: blocks [0,npb) perm scatter (no atomic) ;
//           blocks [npb, npb+nbc) vscan3(rowcounts2->rowstart2) ----
__global__ __launch_bounds__(512) void mk4_kernel(
    const uint32_t* __restrict__ rank1_arr, const uint32_t* __restrict__ start1,
    const uint32_t* __restrict__ slot1, uint32_t* __restrict__ perm,
    const uint32_t* __restrict__ rowcounts2, const uint32_t* __restrict__ bsc2,
    uint32_t* __restrict__ rowstart2, int M, int npb, int nbc) {
    int b = blockIdx.x, t = threadIdx.x;
    if (b < npb) {
        int i = b * 512 + t;
        if (i >= M) return;
        uint32_t r1 = rank1_arr[i];
        perm[start1[r1] + slot1[i]] = i;
        return;
    }
    __shared__ uint32_t s[512];
    vscan3_512(rowcounts2, bsc2, rowstart2, b - npb, M, s, t);
}

// ------- flatten input rows into perm_f grouped by r2, group starts flagged bit31 -------
__global__ __launch_bounds__(512) void flatten_kernel(
    const uint32_t* __restrict__ parent_r2, const uint32_t* __restrict__ counts,
    const uint32_t* __restrict__ start1, const uint32_t* __restrict__ rowstart2,
    const uint32_t* __restrict__ childbase, const uint32_t* __restrict__ perm,
    uint32_t* __restrict__ perm_f, const uint32_t* __restrict__ totals, int M) {
    int i = blockIdx.x * 512 + threadIdx.x;
    if (i >= M) return;
    uint32_t U1 = totals[0];
    if ((uint32_t)i >= U1) return;
    uint32_t r2 = parent_r2[i];
    uint32_t cnt = counts[i];
    uint32_t dst = rowstart2[r2] + childbase[i];
    uint32_t s = start1[i];
    perm_f[dst] = perm[s] | 0x80000000u;               // flag = start of relu group
    for (uint32_t q = 1; q < cnt; ++q) perm_f[dst + q] = perm[s + q];
}

// ---------------- bf16 MFMA GEMM: g = bf16( relu(X) @ W0 ) ----------------
// Barrier-free, one wave = one 16-row tile, grid-stride with 2-deep register
// prefetch. X loads NONTEMPORAL (single-use stream; keep g LLC-resident for
// gather). Wt in LDS fragment-major: conflict-free ds_read_b128 w/ imm offset.
__device__ __forceinline__ void gemm_loadX(const float* __restrict__ X,
                                           int tile, int lm, int kg, f32x4* pf) {
    const char* xb = (const char*)X + ((size_t)tile*16 + lm)*512 + kg*32;
    #pragma unroll
    for (int ks = 0; ks < 4; ++ks) {
        pf[2*ks]   = __builtin_nontemporal_load((const f32x4*)(xb + ks*128));
        pf[2*ks+1] = __builtin_nontemporal_load((const f32x4*)(xb + ks*128 + 16));
    }
}

__device__ __forceinline__ void gemm_compute(const f32x4* pf, const char* wbase,
                                             ushort* __restrict__ g, int tile,
                                             int lm, int kg) {
    bf16x8 af[4];
    #pragma unroll
    for (int ks = 0; ks < 4; ++ks) {
        f32x4 a = pf[2*ks], b = pf[2*ks+1];
        union { uint32_t u[4]; bf16x8 v; } cv;
        cv.u[0] = f2bf1(fmaxf(a[0],0.f)) | (f2bf1(fmaxf(a[1],0.f)) << 16);
        cv.u[1] = f2bf1(fmaxf(a[2],0.f)) | (f2bf1(fmaxf(a[3],0.f)) << 16);
        cv.u[2] = f2bf1(fmaxf(b[0],0.f)) | (f2bf1(fmaxf(b[1],0.f)) << 16);
        cv.u[3] = f2bf1(fmaxf(b[2],0.f)) | (f2bf1(fmaxf(b[3],0.f)) << 16);
        af[ks] = cv.v;
    }
    ushort* grow = g + (size_t)((size_t)tile*16 + 4*kg)*128 + lm;
    #pragma unroll
    for (int n = 0; n < 8; ++n) {
        bf16x8 b0 = *(const bf16x8*)(wbase + n*256);
        bf16x8 b1 = *(const bf16x8*)(wbase + n*256 + 8192);
        bf16x8 b2 = *(const bf16x8*)(wbase + n*256 + 16384);
        bf16x8 b3 = *(const bf16x8*)(wbase + n*256 + 24576);
        f32x4 acc = (f32x4){0.f, 0.f, 0.f, 0.f};
        acc = __builtin_amdgcn_mfma_f32_16x16x32_bf16(af[0], b0, acc, 0, 0, 0);
        acc = __builtin_amdgcn_mfma_f32_16x16x32_bf16(af[1], b1, acc, 0, 0, 0);
        acc = __builtin_amdgcn_mfma_f32_16x16x32_bf16(af[2], b2, acc, 0, 0, 0);
        acc = __builtin_amdgcn_mfma_f32_16x16x32_bf16(af[3], b3, acc, 0, 0, 0);
        #pragma unroll
        for (int r = 0; r < 4; ++r)
            grow[(size_t)r*128 + 16*n] = (ushort)f2bf1(acc[r]);
    }
}

__global__ __launch_bounds__(256) void gemm_kernel(
    const float* __restrict__ X, const ushort* __restrict__ Wt,
    ushort* __restrict__ g, int M) {
    __shared__ __align__(16) ushort wlds[16384];       // 32 KB
    const int t = threadIdx.x;
    {
        // stage Wt: src chunk (row=16n+m, kc) -> dst [ks=kc>>2][kg=kc&3][n][m]
        int sm = t & 15, kc = t >> 4;                  // kc 0..15
        const char* src = (const char*)Wt;
        char* dst = (char*)wlds;
        #pragma unroll
        for (int n = 0; n < 8; ++n) {
            uint4 v = *(const uint4*)(src + n*4096 + sm*256 + kc*16);
            *(uint4*)(dst + (kc>>2)*8192 + (kc&3)*2048 + n*256 + sm*16) = v;
        }
    }
    __syncthreads();                                   // only barrier in kernel
    const int l = t & 63;
    const int lm = l & 15, kg = l >> 4;                // A-frag row / k-group
    const int ntiles = M >> 4;
    const int nw = gridDim.x * 4;
    int tile = blockIdx.x * 4 + (t >> 6);
    const char* wbase = (const char*)wlds + kg*2048 + lm*16;

    f32x4 pfA[8], pfB[8];
    if (tile < ntiles)      gemm_loadX(X, tile, lm, kg, pfA);
    if (tile + nw < ntiles) gemm_loadX(X, tile + nw, lm, kg, pfB);
    while (true) {
        if (tile >= ntiles) break;
        // consume A, then immediately refill A so its loads fly under phase B
        gemm_compute(pfA, wbase, g, tile, lm, kg);
        if (tile + 2*nw < ntiles) gemm_loadX(X, tile + 2*nw, lm, kg, pfA);
        tile += nw;
        if (tile >= ntiles) break;
        gemm_compute(pfB, wbase, g, tile, lm, kg);
        if (tile + 2*nw < ntiles) gemm_loadX(X, tile + 2*nw, lm, kg, pfB);
        tile += nw;
    }
}

// ---------------- flattened gather: out[j] = sum_groups relu(sum_rows g) -------------
// one wave per output row; row list is precomputed (perm_f), group starts flagged bit31
// out stores NONTEMPORAL (205 MB single-use stream; keeps g LLC-resident).
__global__ __launch_bounds__(256) void gather2_kernel(
    const uint32_t* __restrict__ rowstart2, const uint32_t* __restrict__ rowcounts2,
    const uint32_t* __restrict__ perm_f, const ushort* __restrict__ g,
    float* __restrict__ out, int M) {
    int wid = (blockIdx.x * 256 + threadIdx.x) >> 6;
    wid = __builtin_amdgcn_readfirstlane(wid);         // force wave-uniform SGPR
    int lane = threadIdx.x & 63;
    if (wid >= M) return;
    const uint32_t* G = (const uint32_t*)g;
    float accx = 0.f, accy = 0.f;
    uint32_t n = rowcounts2[wid];
    if (n) {
        uint32_t s = rowstart2[wid];
        // one coalesced load grabs up to 64 row entries for the whole wave
        uint32_t ev = (lane < (int)n) ? perm_f[s + lane] : 0u;
        float sx = 0.f, sy = 0.f;
        uint32_t ecur = (uint32_t)__shfl((int)ev, 0);
        uint32_t pk = G[(size_t)(ecur & 0x7FFFFFFFu) * 64 + lane];
        for (uint32_t q = 1; q < n; ++q) {
            uint32_t en = (q < 64u) ? (uint32_t)__shfl((int)ev, (int)q)
                                    : perm_f[s + q];
            // issue next row's load before consuming current (keeps 2 loads in flight)
            uint32_t pkn = G[(size_t)(en & 0x7FFFFFFFu) * 64 + lane];
            sx += __uint_as_float(pk << 16);
            sy += __uint_as_float(pk & 0xFFFF0000u);
            if (en >> 31) {                            // new relu group begins at row q
                accx += fmaxf(sx, 0.f); accy += fmaxf(sy, 0.f);
                sx = 0.f; sy = 0.f;
            }
            pk = pkn;
        }
        sx += __uint_as_float(pk << 16);
        sy += __uint_as_float(pk & 0xFFFF0000u);
        accx += fmaxf(sx, 0.f);
        accy += fmaxf(sy, 0.f);
    }
    f32x2 o; o[0] = accx; o[1] = accy;
    __builtin_nontemporal_store(o, (f32x2*)out + (size_t)wid * 64 + lane);
}

extern "C" void kernel_launch(void* const* d_in, const int* in_sizes, int n_in,
                              void* d_out, int out_size, void* d_ws, size_t ws_size,
                              hipStream_t stream) {
    const float* X      = (const float*)d_in[0];
    const int*   coords = (const int*)d_in[1];
    const float* W      = (const float*)d_in[2];
    const int M = in_sizes[0] / C;               // 400000

    const int NW1 = 1 << 19;                     // 2^24-bit bitmap -> 524288 words
    const int NW2 = 1 << 15;                     // 2^20-bit bitmap -> 32768 words
    const int NBC = (M + 1023) / 1024;           // 391 (1024 elems per scan block)
    const int NPB = (M + 511) / 512;             // 782 (512-thread element kernels)

    char* ws = (char*)d_ws;
    size_t off = 0;
    ushort*   g         = (ushort*)(ws + off);   off += (size_t)M * C * 2;   // 102.4 MB
    // ---- contiguous zeroed region: bm1 | bm2 | counts | rowcounts2 ----
    uint32_t* bm1       = (uint32_t*)(ws + off); off += (size_t)NW1 * 4;
    uint32_t* bm2       = (uint32_t*)(ws + off); off += (size_t)NW2 * 4;
    uint32_t* counts    = (uint32_t*)(ws + off); off += (size_t)M * 4;
    uint32_t* rowcounts2= (uint32_t*)(ws + off); off += (size_t)M * 4;
    const size_t zero_off   = (size_t)M * C * 2;
    const size_t zero_bytes = off - zero_off;    // 16B multiple
    // ---- never-zeroed scratch ----
    uint32_t* wp1       = (uint32_t*)(ws + off); off += (size_t)NW1 * 4;
    uint32_t* wp2       = (uint32_t*)(ws + off); off += (size_t)NW2 * 4;
    uint32_t* bs1       = (uint32_t*)(ws + off); off += 512 * 4;
    uint32_t* bs2       = (uint32_t*)(ws + off); off += 512 * 4;
    uint32_t* bsc       = (uint32_t*)(ws + off); off += 512 * 4;
    uint32_t* bsc2      = (uint32_t*)(ws + off); off += 512 * 4;
    uint32_t* totals    = (uint32_t*)(ws + off); off += 4 * 4;
    uint32_t* start1    = (uint32_t*)(ws + off); off += (size_t)M * 4;
    uint32_t* rank1_arr = (uint32_t*)(ws + off); off += (size_t)M * 4;
    uint32_t* slot1     = (uint32_t*)(ws + off); off += (size_t)M * 4;
    uint32_t* perm      = (uint32_t*)(ws + off); off += (size_t)M * 4;
    uint32_t* parent_r2 = (uint32_t*)(ws + off); off += (size_t)M * 4;
    uint32_t* childbase = (uint32_t*)(ws + off); off += (size_t)M * 4;
    uint32_t* rowstart2 = (uint32_t*)(ws + off); off += (size_t)M * 4;
    ushort*   Wt        = (ushort*)(ws + off);   off += (size_t)C * C * 2;
    uint32_t* perm_f    = rank1_arr;             // rank1_arr dead after mk4 (perm)

    const int NQ  = (int)(zero_bytes / 16);      // uint4 quads to zero
    const int NZB = (NQ + 511) / 512;            // zero blocks

    // 1: zero atomic buffers + convert W (merged; replaces hipMemsetAsync)
    zeroconv_kernel<<<NZB + 32, 512, 0, stream>>>((uint4*)(ws + zero_off), NQ, W, Wt, NZB);
    // 2: mark bitmaps
    mark_kernel<<<NPB, 512, 0, stream>>>(coords, bm1, bm2, M);
    // 3-5: bitmap rank scans for bm1 and bm2 (merged per phase)
    mscan1_kernel<<<544, 512, 0, stream>>>(bm1, bs1, bm2, bs2);
    mscan2_kernel<<<2, 512, 0, stream>>>(bs1, bs2, totals);
    mscan3_kernel<<<544, 512, 0, stream>>>(bm1, bs1, wp1, bm2, bs2, wp2);
    // 6: per-row rank + counts (+ slot via atomic return)
    count_kernel<<<NPB, 512, 0, stream>>>(coords, bm1, wp1, counts, rank1_arr, slot1, M);
    // 7-10: {vscan1(counts) || childsum}, {scan2(bsc) || vscan1(rowcounts2)},
    //       {vscan3(start1) || scan2(bsc2)}, {perm || vscan3(rowstart2)}
    mk1_kernel<<<NBC + NW1/512, 512, 0, stream>>>(counts, bsc, bm1, wp1, bm2, wp2,
                                                  parent_r2, rowcounts2, childbase,
                                                  M, NBC, NW1);
    mk2_kernel<<<1 + NBC, 512, 0, stream>>>(bsc, totals, rowcounts2, bsc2, M, NBC);
    mk3_kernel<<<NBC + 1, 512, 0, stream>>>(counts, bsc, start1, bsc2, totals, M, NBC);
    mk4_kernel<<<NPB + NBC, 512, 0, stream>>>(rank1_arr, start1, slot1, perm,
                                              rowcounts2, bsc2, rowstart2, M, NPB, NBC);
    // 11: flatten rows grouped by r2 (atomic-free)
    flatten_kernel<<<NPB, 512, 0, stream>>>(
        parent_r2, counts, start1, rowstart2, childbase, perm, perm_f, totals, M);
    // 12: GEMM, 13: gather
    gemm_kernel<<<1280, 256, 0, stream>>>(X, Wt, g, M);
    gather2_kernel<<<(M + 3) / 4, 256, 0, stream>>>(
        rowstart2, rowcounts2, perm_f, g, (float*)d_out, M);
}